// Round 8
// baseline (422.699 us; speedup 1.0000x reference)
//
#include <hip/hip_runtime.h>

// ---------------------------------------------------------------------------
// CorefPairScorer: B=4, T=4096, D=768, N=256, HID=200 (padded to 256)
// h1(i,j) = relu(A[i] + Bv[j] + (emb_i*emb_j)@W1bot + b1)
// h2 = relu(h1@W2 + b2); s = h2@W3 + b3; masked softmax rows.
// R8: R7 killed the spill (WRITE 150MB->0.5MB) but exposed the next wall:
//     L1/L2 line throughput + 2 waves/SIMD. Restructure: HID padded to 256
//     (16 ntiles); 4 waves = 4 disjoint n-groups (no duplicate W loads),
//     each wave 4 Mtiles x 4 ntiles (acc[4][4]) -> 4x W-reuse per fragment
//     load. h1 LDS row-major stride 264 (writes 2-way free, b128 reads
//     even). LDS 52KB, ~125 live regs -> target 3 blocks/CU.
// ---------------------------------------------------------------------------

#define NB 4
#define NN 256
#define DD 768
#define TT 4096
#define HP2 256          // padded hidden: 16 ntiles
#define NT2 16
#define KT1 24
#define KT2 8
#define TRI 136
#define HSTR 264         // h1 LDS row stride (shorts): writes 2-way, reads even
#define MTS (16 * HSTR)  // 4224 shorts per Mtile slot
#define ABS 512          // AB row stride (bf16): [A(256) | B(256)]

typedef __attribute__((ext_vector_type(8))) short short8;
typedef __attribute__((ext_vector_type(4))) float f32x4;

union FragU { uint4 u; short8 s; };

__device__ __forceinline__ float bf2f(unsigned short x) {
    return __uint_as_float(((unsigned int)x) << 16);
}
__device__ __forceinline__ unsigned short f2bf(float f) {
    unsigned int u = __float_as_uint(f);
    u += 0x7fffu + ((u >> 16) & 1u);   // RNE
    return (unsigned short)(u >> 16);
}
__device__ __forceinline__ float blo(unsigned int v) { return __uint_as_float(v << 16); }
__device__ __forceinline__ float bhi(unsigned int v) { return __uint_as_float(v & 0xffff0000u); }
__device__ __forceinline__ unsigned int mulpack(unsigned int a, float bl, float bh) {
    unsigned int m0 = __float_as_uint(blo(a) * bl);
    unsigned int m1 = __float_as_uint(bhi(a) * bh);
    return __builtin_amdgcn_perm(m1, m0, 0x07060302u);
}

// ---------------------------------------------------------------------------
// K0: prep. Blocks 0..23: w1n (node GEMM weights, 28 ntiles of [A|B] 448).
//     Blocks 24..47: w1s (pair phase1, 16 ntiles of 256, kt = bx-24).
//     Blocks 48..55: w2s (pair phase2, 16 ntiles, kk = bx-48).
//     Blocks 56..1079: gather emb + fp32->bf16.
//     All W reads coalesced via LDS-tiled transpose.
// ---------------------------------------------------------------------------
__global__ __launch_bounds__(256) void prep_all(
    const float* __restrict__ W1, const float* __restrict__ W2,
    const float* __restrict__ ee, const int* __restrict__ eidx,
    unsigned short* __restrict__ w1n,
    unsigned short* __restrict__ w1s,
    unsigned short* __restrict__ w2s,
    unsigned short* __restrict__ emb) {
    int bx = blockIdx.x, tid = threadIdx.x;
    if (bx >= 56) {                 // gather + cast
        int g = bx - 56;
        int b = g >> 8, n = g & 255;
        int t = eidx[b * NN + n];
        const float* src = ee + ((size_t)b * TT + t) * DD;
        unsigned short* dst = emb + ((size_t)b * NN + n) * DD;
        for (int e = tid; e < DD; e += 256) dst[e] = f2bf(src[e]);
        return;
    }
    __shared__ unsigned short plds[32 * 452];   // 28928 B
    if (bx < 24) {                  // w1n: kt tile of [W1top | W1mid], 448 cols
        int kt = bx;
        for (int idx = tid; idx < 32 * 448; idx += 256) {
            int r = idx / 448, cc = idx - r * 448;
            float v;
            if (cc < 224) v = (cc < 200) ? W1[(size_t)(kt * 32 + r) * 200 + cc] : 0.f;
            else { int n = cc - 224; v = (n < 200) ? W1[(size_t)(768 + kt * 32 + r) * 200 + n] : 0.f; }
            plds[r * 452 + cc] = f2bf(v);
        }
        __syncthreads();
        for (int o = tid; o < 28 * 512; o += 256) {
            int nt = o >> 9, lane = (o >> 3) & 63, j = o & 7;
            int kl = ((lane >> 4) << 3) + j, n = nt * 16 + (lane & 15);
            w1n[(size_t)kt * 14336 + o] = plds[kl * 452 + n];
        }
    } else if (bx < 48) {           // w1s: W1bot kt tile, 256 cols (200 real)
        int kt = bx - 24;
        for (int idx = tid; idx < 32 * 256; idx += 256) {
            int r = idx >> 8, cc = idx & 255;
            float v = (cc < 200) ? W1[(size_t)(1536 + kt * 32 + r) * 200 + cc] : 0.f;
            plds[r * 260 + cc] = f2bf(v);
        }
        __syncthreads();
        for (int o = tid; o < 16 * 512; o += 256) {
            int nt = o >> 9, lane = (o >> 3) & 63, j = o & 7;
            int kl = ((lane >> 4) << 3) + j, n = nt * 16 + (lane & 15);
            w1s[(size_t)kt * 8192 + o] = plds[kl * 260 + n];
        }
    } else {                        // w2s: W2 kk tile (k<200 real), 256 cols
        int kk = bx - 48;
        for (int idx = tid; idx < 32 * 256; idx += 256) {
            int r = idx >> 8, cc = idx & 255;
            int k = kk * 32 + r;
            float v = (k < 200 && cc < 200) ? W2[(size_t)k * 200 + cc] : 0.f;
            plds[r * 260 + cc] = f2bf(v);
        }
        __syncthreads();
        for (int o = tid; o < 16 * 512; o += 256) {
            int nt = o >> 9, lane = (o >> 3) & 63, j = o & 7;
            int kl = ((lane >> 4) << 3) + j, n = nt * 16 + (lane & 15);
            w2s[(size_t)kk * 8192 + o] = plds[kl * 260 + n];
        }
    }
}

// ---------------------------------------------------------------------------
// K2: AB = emb(1024x768) @ [W1top|W1mid](768x448), bf16 MFMA, bf16 out.
//     Output cols remapped: A -> 0..223 (pad 224..255 unwritten),
//     B -> 256..479 (ABS 512).
// ---------------------------------------------------------------------------
__global__ __launch_bounds__(256)
void node_mfma(const unsigned short* __restrict__ emb,
               const unsigned short* __restrict__ w1n,
               unsigned short* __restrict__ AB) {
    int tid = threadIdx.x, lane = tid & 63, w = tid >> 6;
    int q = lane >> 4, c = lane & 15;
    int mt = w >> 1;
    int ng = ((blockIdx.x & 1) << 1) | (w & 1);
    int m0 = (blockIdx.x >> 1) * 32 + mt * 16;
    const uint4* ga = (const uint4*)emb + (size_t)(m0 + c) * 96;
    const uint4* gb = (const uint4*)w1n;

    f32x4 acc[7];
#pragma unroll
    for (int n = 0; n < 7; ++n) acc[n] = (f32x4){0.f, 0.f, 0.f, 0.f};

    for (int kt = 0; kt < KT1; ++kt) {
        FragU a; a.u = ga[kt * 4 + q];
#pragma unroll
        for (int n = 0; n < 7; ++n) {
            FragU bb; bb.u = gb[((kt * 28 + ng * 7 + n) << 6) + lane];
            acc[n] = __builtin_amdgcn_mfma_f32_16x16x32_bf16(a.s, bb.s, acc[n], 0, 0, 0);
        }
    }
#pragma unroll
    for (int n = 0; n < 7; ++n) {
        int col = (ng * 7 + n) * 16 + c;
        int oc = (col < 224) ? col : col + 32;
#pragma unroll
        for (int rr = 0; rr < 4; ++rr)
            AB[(size_t)(m0 + q * 4 + rr) * ABS + oc] = f2bf(acc[n][rr]);
    }
}

// ---------------------------------------------------------------------------
// K3: fused pair MLP per 16x16 (i,j) tile. 256 threads = 4 waves.
//   Wave w = n-group ng (4 ntiles: cols ng*64..+63). 4 passes of 4 Mtiles;
//   every wave covers all 4 Mtiles (acc[4][4]) -> each W-fragment load is
//   reused by 4 MFMAs and no two waves load the same fragment.
// ---------------------------------------------------------------------------
__global__ __launch_bounds__(256)
void pair_mlp(
    const unsigned short* __restrict__ emb,
    const unsigned short* __restrict__ w1s,
    const unsigned short* __restrict__ w2s,
    const unsigned short* __restrict__ AB,
    const float* __restrict__ b1, const float* __restrict__ b2,
    const float* __restrict__ W3, const float* __restrict__ b3,
    float* __restrict__ S) {
    int z = blockIdx.x;
    int b = z / TRI;
    int r = z % TRI;
    int ti = (int)((sqrtf(8.f * (float)r + 1.f) - 1.f) * 0.5f);
    while ((ti + 1) * (ti + 2) / 2 <= r) ++ti;
    while (ti * (ti + 1) / 2 > r) --ti;
    int tj = r - ti * (ti + 1) / 2;
    int i0 = ti << 4, j0 = tj << 4;

    int tid = threadIdx.x;
    int lane = tid & 63;
    int ng = tid >> 6;                // wave = n-group 0..3
    int q = lane >> 4, c = lane & 15;

    __shared__ unsigned short smH[4 * MTS];    // 33792 B: h1 [m][k] stride 264
    __shared__ unsigned short Ai[16 * HP2];    //  8192 B
    __shared__ unsigned short Bv[16 * HP2];    //  8192 B
    __shared__ unsigned short sred[4][256];    //  2048 B (bf16 partials)

    // ---- stage Ai / (Bv + b1) (pad cols 224..255 zeroed) ----
    for (int m = 0; m < 16; ++m) {
        for (int h = tid; h < HP2; h += 256) {
            Ai[m * HP2 + h] = (h < 224) ? AB[(size_t)(b * NN + i0 + m) * ABS + h] : (unsigned short)0;
            float bv = (h < 224) ? bf2f(AB[(size_t)(b * NN + j0 + m) * ABS + 256 + h]) : 0.f;
            bv += (h < 200) ? b1[h] : 0.f;
            Bv[m * HP2 + h] = f2bf(bv);
        }
    }

    const uint4* w1f = (const uint4*)w1s;
    const uint4* w2f = (const uint4*)w2s;
    const uint4* gI  = (const uint4*)(emb + ((size_t)b * NN + i0) * DD);
    const uint4* gJc = (const uint4*)(emb + ((size_t)b * NN + j0 + c) * DD);

    for (int pass = 0; pass < 4; ++pass) {
        // ---- phase 1: acc[4][4] over K=768 ----
        f32x4 acc[4][4];
#pragma unroll
        for (int t = 0; t < 4; ++t)
#pragma unroll
            for (int n = 0; n < 4; ++n)
                acc[t][n] = (f32x4){0.f, 0.f, 0.f, 0.f};

        for (int kt = 0; kt < KT1; ++kt) {
            uint4 bfr[4];
#pragma unroll
            for (int n = 0; n < 4; ++n)
                bfr[n] = w1f[(kt * NT2 + ng * 4 + n) * 64 + lane];
            uint4 ej = gJc[kt * 4 + q];
            float exl = blo(ej.x), exh = bhi(ej.x);
            float eyl = blo(ej.y), eyh = bhi(ej.y);
            float ezl = blo(ej.z), ezh = bhi(ej.z);
            float ewl = blo(ej.w), ewh = bhi(ej.w);
#pragma unroll
            for (int t = 0; t < 4; ++t) {
                int tg = (pass << 2) + t;               // i-row Mtile
                uint4 ei = gI[tg * 96 + kt * 4 + q];    // quad-broadcast
                FragU a;
                a.u.x = mulpack(ei.x, exl, exh);
                a.u.y = mulpack(ei.y, eyl, eyh);
                a.u.z = mulpack(ei.z, ezl, ezh);
                a.u.w = mulpack(ei.w, ewl, ewh);
#pragma unroll
                for (int n = 0; n < 4; ++n) {
                    FragU bb; bb.u = bfr[n];
                    acc[t][n] = __builtin_amdgcn_mfma_f32_16x16x32_bf16(a.s, bb.s, acc[t][n], 0, 0, 0);
                }
            }
        }

        // ---- epilogue: h1 = relu(acc + Ai + Bv) -> smH[m][h], stride 264 ----
        __syncthreads();   // prev pass's phase-2 readers done (+ staging, pass 0)
#pragma unroll
        for (int t = 0; t < 4; ++t) {
            int tg = (pass << 2) + t;
#pragma unroll
            for (int n = 0; n < 4; ++n) {
                int h = ((ng * 4 + n) << 4) + c;
                float base = bf2f(Ai[tg * HP2 + h]);
#pragma unroll
                for (int rr = 0; rr < 4; ++rr) {
                    float v = acc[t][n][rr] + base + bf2f(Bv[(q * 4 + rr) * HP2 + h]);
                    v = fmaxf(v, 0.f);
                    smH[t * MTS + (q * 4 + rr) * HSTR + h] = f2bf(v);
                }
            }
        }
        __syncthreads();

        // ---- phase 2: acc2[4][4] over K=256 from smH ----
        f32x4 acc2[4][4];
#pragma unroll
        for (int t = 0; t < 4; ++t)
#pragma unroll
            for (int n = 0; n < 4; ++n)
                acc2[t][n] = (f32x4){0.f, 0.f, 0.f, 0.f};

        for (int kk = 0; kk < KT2; ++kk) {
            uint4 bfr2[4];
#pragma unroll
            for (int n = 0; n < 4; ++n)
                bfr2[n] = w2f[(kk * NT2 + ng * 4 + n) * 64 + lane];
#pragma unroll
            for (int t = 0; t < 4; ++t) {
                FragU a2;
                a2.u = *(const uint4*)(&smH[t * MTS + c * HSTR + kk * 32 + q * 8]);
#pragma unroll
                for (int n = 0; n < 4; ++n) {
                    FragU bb; bb.u = bfr2[n];
                    acc2[t][n] = __builtin_amdgcn_mfma_f32_16x16x32_bf16(a2.s, bb.s, acc2[t][n], 0, 0, 0);
                }
            }
        }

        // ---- phase 3: s = relu(h2 + b2) . W3, reduce over this wave's cols ----
#pragma unroll
        for (int t = 0; t < 4; ++t) {
#pragma unroll
            for (int rr = 0; rr < 4; ++rr) {
                float part = 0.f;
#pragma unroll
                for (int n = 0; n < 4; ++n) {
                    int h = ((ng * 4 + n) << 4) + c;
                    float b2v = (h < 200) ? b2[h] : 0.f;
                    float w3v = (h < 200) ? W3[h] : 0.f;
                    float hv = fmaxf(acc2[t][n][rr] + b2v, 0.f);
                    part += hv * w3v;
                }
                part += __shfl_xor(part, 1);
                part += __shfl_xor(part, 2);
                part += __shfl_xor(part, 4);
                part += __shfl_xor(part, 8);
                if (c == 0) {
                    int p = (((pass << 2) + t) << 4) + q * 4 + rr;
                    sred[ng][p] = f2bf(part);
                }
            }
        }
    }
    __syncthreads();
    {   // final: S[b][i0+ii][j0+jj]; ii = Mtile index, jj = row within tile
        int ii = tid >> 4, jj = tid & 15;
        float s = bf2f(sred[0][tid]) + bf2f(sred[1][tid]) +
                  bf2f(sred[2][tid]) + bf2f(sred[3][tid]) + b3[0];
        S[((size_t)b * NN + i0 + ii) * NN + j0 + jj] = s;
    }
}

// ---------------------------------------------------------------------------
// K4: masked softmax per row; diag logit = 0; invalid -> -1000
// ---------------------------------------------------------------------------
__global__ __launch_bounds__(256) void softmax_rows(const float* __restrict__ S,
                                                    float* __restrict__ out) {
    int b = blockIdx.x >> 8, i = blockIdx.x & 255;
    int j = threadIdx.x;
    int lane = j & 63, w = j >> 6;
    __shared__ float red[16];
    float x = (j < i) ? S[((size_t)b * NN + i) * NN + j] : ((j == i) ? 0.f : -1e30f);
    float m = x;
#pragma unroll
    for (int off = 32; off; off >>= 1) m = fmaxf(m, __shfl_xor(m, off));
    if (lane == 0) red[w] = m;
    __syncthreads();
    float mx = fmaxf(fmaxf(red[0], red[1]), fmaxf(red[2], red[3]));
    float e = (j <= i) ? __expf(x - mx) : 0.f;
    float s = e;
#pragma unroll
    for (int off = 32; off; off >>= 1) s += __shfl_xor(s, off);
    if (lane == 0) red[8 + w] = s;
    __syncthreads();
    float sum = red[8] + red[9] + red[10] + red[11];
    out[((size_t)b * NN + i) * NN + j] = (j <= i) ? (e / sum) : -1000.0f;
}

// ---------------------------------------------------------------------------
extern "C" void kernel_launch(void* const* d_in, const int* in_sizes, int n_in,
                              void* d_out, int out_size, void* d_ws, size_t ws_size,
                              hipStream_t stream) {
    const float* ee  = (const float*)d_in[0];
    const int*   eidx = (const int*)d_in[1];
    const float* W1  = (const float*)d_in[2];
    const float* b1  = (const float*)d_in[3];
    const float* W2  = (const float*)d_in[4];
    const float* b2  = (const float*)d_in[5];
    const float* W3  = (const float*)d_in[6];
    const float* b3  = (const float*)d_in[7];
    float* out = (float*)d_out;

    char* p = (char*)d_ws;
    unsigned short* emb = (unsigned short*)p; p += (size_t)NB * NN * DD * 2;       // 1.5 MB
    unsigned short* w1s = (unsigned short*)p; p += (size_t)KT1 * 8192 * 2;         // 384 KB
    unsigned short* w2s = (unsigned short*)p; p += (size_t)KT2 * 8192 * 2;         // 128 KB
    unsigned short* AB  = (unsigned short*)p; p += (size_t)NB * NN * ABS * 2;      // 1 MB
    // w1n (672 KB, used only prep->node_mfma) aliases S (1 MB, used pair_mlp->softmax)
    unsigned short* w1n = (unsigned short*)p;
    float* S = (float*)p;  p += (size_t)NB * NN * NN * 4;                           // 1 MB

    prep_all<<<1080, 256, 0, stream>>>(W1, W2, ee, eidx, w1n, w1s, w2s, emb);
    node_mfma<<<64, 256, 0, stream>>>(emb, w1n, AB);
    pair_mlp<<<NB * TRI, 256, 0, stream>>>(emb, w1s, w2s, AB, b1, b2, W3, b3, S);
    softmax_rows<<<NB * NN, 256, 0, stream>>>(S, out);
}